// Round 5
// baseline (12051.113 us; speedup 1.0000x reference)
//
#include <hip/hip_runtime.h>
#include <math.h>

#define B_DIM 4
#define T_DIM 4096
#define C_DIM 1024
#define BT    (B_DIM*T_DIM)              // 16384
#define BTC   ((size_t)BT*(size_t)C_DIM) // 16777216

// ---------------------------------------------------------------------------
// Generic fp32 tiled matmul body (shared by single and batched wrappers).
//   TB=1: C[m,n] = sum_k A[m,k]*B[n,k]      (B stored [N,K] row-major)
//   TB=0: C[m,n] = sum_k A[m,k]*B[k,n]
//   HAS_A2: A_eff[m,k] = A[m,k]*A2[m,k]
//   out = alpha*acc + (HAS_D ? beta*D[m,n] : 0)
//   lda: row stride (elements) of A/A2 — 2048 GEMMs the even/odd rows of a
//        [16384][1024] matrix.
// ---------------------------------------------------------------------------
template<int BM, int BN, int BK, int TM, int TN, bool TB, bool HAS_A2, bool HAS_D>
__device__ __forceinline__ void mm_body(const float* __restrict__ A,
                                        const float* __restrict__ Bmat,
                                        const float* __restrict__ A2,
                                        const float* __restrict__ Dmat,
                                        float* __restrict__ C,
                                        int M, int N, int K, int lda,
                                        float alpha, float beta)
{
    constexpr int NG = TN / 4;
    __shared__ float As[BK][BM + 4];
    __shared__ float Bs[BK][BN + 4];

    const int tid = threadIdx.x;
    const int m0 = blockIdx.y * BM;
    const int n0 = blockIdx.x * BN;
    const int tx = tid & 15;
    const int ty = tid >> 4;

    float acc[TM][TN];
#pragma unroll
    for (int i = 0; i < TM; ++i)
#pragma unroll
        for (int j = 0; j < TN; ++j) acc[i][j] = 0.f;

    for (int k0 = 0; k0 < K; k0 += BK) {
        {
            const int r0 = tid >> 2;
            const int kq = (tid & 3) * 4;
#pragma unroll
            for (int r = 0; r < BM; r += 64) {
                const int row = r + r0;
                float4 a = *(const float4*)(A + (size_t)(m0 + row) * lda + k0 + kq);
                if (HAS_A2) {
                    float4 a2 = *(const float4*)(A2 + (size_t)(m0 + row) * lda + k0 + kq);
                    a.x *= a2.x; a.y *= a2.y; a.z *= a2.z; a.w *= a2.w;
                }
                As[kq + 0][row] = a.x; As[kq + 1][row] = a.y;
                As[kq + 2][row] = a.z; As[kq + 3][row] = a.w;
            }
        }
        if (TB) {
            const int r0 = tid >> 2;
            const int kq = (tid & 3) * 4;
#pragma unroll
            for (int r = 0; r < BN; r += 64) {
                const int row = r + r0;
                float4 b = *(const float4*)(Bmat + (size_t)(n0 + row) * K + k0 + kq);
                Bs[kq + 0][row] = b.x; Bs[kq + 1][row] = b.y;
                Bs[kq + 2][row] = b.z; Bs[kq + 3][row] = b.w;
            }
        } else {
            constexpr int CPR = BN / 4;
            constexpr int RPP = 256 / CPR;
            const int rr = tid / CPR;
            const int cc = (tid % CPR) * 4;
#pragma unroll
            for (int r = 0; r < BK; r += RPP) {
                float4 b = *(const float4*)(Bmat + (size_t)(k0 + r + rr) * N + n0 + cc);
                *(float4*)(&Bs[r + rr][cc]) = b;
            }
        }
        __syncthreads();

#pragma unroll
        for (int kk = 0; kk < BK; ++kk) {
            float a[TM], b[TN];
#pragma unroll
            for (int i = 0; i < TM; i += 4)
                *(float4*)(&a[i]) = *(const float4*)(&As[kk][ty * TM + i]);
#pragma unroll
            for (int g = 0; g < NG; ++g)
                *(float4*)(&b[g * 4]) = *(const float4*)(&Bs[kk][g * (BN / 2) + tx * 4]);
#pragma unroll
            for (int i = 0; i < TM; ++i)
#pragma unroll
                for (int j = 0; j < TN; ++j)
                    acc[i][j] = fmaf(a[i], b[j], acc[i][j]);
        }
        __syncthreads();
    }

#pragma unroll
    for (int i = 0; i < TM; ++i) {
        const size_t rbase = (size_t)(m0 + ty * TM + i) * N + n0;
#pragma unroll
        for (int g = 0; g < NG; ++g) {
            const size_t cb = rbase + g * (BN / 2) + tx * 4;
            float4 o;
            o.x = alpha * acc[i][g * 4 + 0];
            o.y = alpha * acc[i][g * 4 + 1];
            o.z = alpha * acc[i][g * 4 + 2];
            o.w = alpha * acc[i][g * 4 + 3];
            if (HAS_D) {
                float4 d4 = *(const float4*)(Dmat + cb);
                o.x = fmaf(beta, d4.x, o.x); o.y = fmaf(beta, d4.y, o.y);
                o.z = fmaf(beta, d4.z, o.z); o.w = fmaf(beta, d4.w, o.w);
            }
            *(float4*)(C + cb) = o;
        }
    }
}

template<int BM, int BN, int BK, int TM, int TN, bool TB, bool HAS_A2, bool HAS_D>
__launch_bounds__(256)
__global__ void mm_kernel(const float* __restrict__ A, const float* __restrict__ Bmat,
                          const float* __restrict__ A2, const float* __restrict__ Dmat,
                          float* __restrict__ C, int M, int N, int K, int lda,
                          float alpha, float beta)
{
    mm_body<BM,BN,BK,TM,TN,TB,HAS_A2,HAS_D>(A, Bmat, A2, Dmat, C, M, N, K, lda, alpha, beta);
}

// batched pair via blockIdx.z
template<int BM, int BN, int BK, int TM, int TN, bool TB, bool HAS_A2, bool HAS_D>
__launch_bounds__(256)
__global__ void mm2_kernel(const float* A0, const float* A1,
                           const float* B0, const float* B1,
                           const float* D0, const float* D1,
                           float* C0, float* C1,
                           int M, int N, int K, int lda, float alpha, float beta)
{
    const int z = blockIdx.z;
    mm_body<BM,BN,BK,TM,TN,TB,HAS_A2,HAS_D>(z ? A1 : A0, z ? B1 : B0, nullptr,
                                            z ? D1 : D0, z ? C1 : C0,
                                            M, N, K, lda, alpha, beta);
}

// ---------------------------------------------------------------------------
// Newton-Schulz helpers (fallback path)
// ---------------------------------------------------------------------------
__global__ void norm2_kernel(const float* __restrict__ W, float* __restrict__ out, int n)
{
    float ss = 0.f;
    for (int i = (blockIdx.x * 256 + threadIdx.x) * 4; i < n; i += gridDim.x * 256 * 4) {
        float4 w = *(const float4*)(W + i);
        ss += w.x * w.x + w.y * w.y + w.z * w.z + w.w * w.w;
    }
#pragma unroll
    for (int off = 32; off > 0; off >>= 1) ss += __shfl_xor(ss, off);
    __shared__ float red[4];
    if ((threadIdx.x & 63) == 0) red[threadIdx.x >> 6] = ss;
    __syncthreads();
    if (threadIdx.x == 0) atomicAdd(out, red[0] + red[1] + red[2] + red[3]);
}

__global__ void scale_kernel(const float* __restrict__ W, const float* __restrict__ norm2,
                             float* __restrict__ X, int n)
{
    const float s = 1.0f / (sqrtf(*norm2) + 1e-8f);
    const int i = (blockIdx.x * 256 + threadIdx.x) * 4;
    if (i < n) {
        float4 w = *(const float4*)(W + i);
        w.x *= s; w.y *= s; w.z *= s; w.w *= s;
        *(float4*)(X + i) = w;
    }
}

// ---------------------------------------------------------------------------
// Persistent Newton-Schulz kernel: 256 WGs (1/CU), 27 grid barriers replace
// ~31 serially-dependent small dispatches (~35-45us launch overhead each).
// Cross-XCD visibility of plain stores: __threadfence() (agent fence ->
// L2 writeback/invalidate) around the sense-reversing barrier.
// Each WG owns one 64x64 tile index for BOTH matrices (lh & rh).
// ---------------------------------------------------------------------------
__device__ __forceinline__ void ns_gbar(unsigned int* cnt, unsigned int* gen)
{
    __syncthreads();
    if (threadIdx.x == 0) {
        __threadfence();   // publish our WG's stores past XCD L2
        unsigned g = __hip_atomic_load(gen, __ATOMIC_RELAXED, __HIP_MEMORY_SCOPE_AGENT);
        unsigned a = __hip_atomic_fetch_add(cnt, 1u, __ATOMIC_ACQ_REL,
                                            __HIP_MEMORY_SCOPE_AGENT);
        if (a == 255u) {
            __hip_atomic_store(cnt, 0u, __ATOMIC_RELAXED, __HIP_MEMORY_SCOPE_AGENT);
            __hip_atomic_store(gen, g + 1u, __ATOMIC_RELEASE, __HIP_MEMORY_SCOPE_AGENT);
        } else {
            while (__hip_atomic_load(gen, __ATOMIC_ACQUIRE,
                                     __HIP_MEMORY_SCOPE_AGENT) == g)
                __builtin_amdgcn_s_sleep(2);
        }
        __threadfence();   // invalidate stale lines before consuming others' stores
    }
    __syncthreads();
}

// 64x64 tile GEMM, K=1024, 256 threads. tb: B stored [N][K] (dot of rows).
__device__ __forceinline__ void ns_tile(const float* __restrict__ A,
                                        const float* __restrict__ Bm,
                                        const float* __restrict__ D,
                                        float* __restrict__ Cc,
                                        int m0, int n0, bool tb, bool has_d,
                                        float alpha, float beta,
                                        float (*As)[68], float (*Bs)[68])
{
    const int tid = threadIdx.x;
    const int tx = tid & 15;
    const int ty = tid >> 4;
    float acc[4][4];
#pragma unroll
    for (int i = 0; i < 4; ++i)
#pragma unroll
        for (int j = 0; j < 4; ++j) acc[i][j] = 0.f;

    for (int k0 = 0; k0 < 1024; k0 += 16) {
        {
            const int r0 = tid >> 2;
            const int kq = (tid & 3) * 4;
            float4 a = *(const float4*)(A + (size_t)(m0 + r0) * 1024 + k0 + kq);
            As[kq + 0][r0] = a.x; As[kq + 1][r0] = a.y;
            As[kq + 2][r0] = a.z; As[kq + 3][r0] = a.w;
            if (tb) {
                float4 b = *(const float4*)(Bm + (size_t)(n0 + r0) * 1024 + k0 + kq);
                Bs[kq + 0][r0] = b.x; Bs[kq + 1][r0] = b.y;
                Bs[kq + 2][r0] = b.z; Bs[kq + 3][r0] = b.w;
            } else {
                const int rr = tid >> 4;
                const int cc = (tid & 15) * 4;
                float4 b = *(const float4*)(Bm + (size_t)(k0 + rr) * 1024 + n0 + cc);
                *(float4*)(&Bs[rr][cc]) = b;
            }
        }
        __syncthreads();
#pragma unroll
        for (int kk = 0; kk < 16; ++kk) {
            float a[4], b[4];
            *(float4*)(&a[0]) = *(const float4*)(&As[kk][ty * 4]);
            *(float4*)(&b[0]) = *(const float4*)(&Bs[kk][tx * 4]);
#pragma unroll
            for (int i = 0; i < 4; ++i)
#pragma unroll
                for (int j = 0; j < 4; ++j)
                    acc[i][j] = fmaf(a[i], b[j], acc[i][j]);
        }
        __syncthreads();
    }

#pragma unroll
    for (int i = 0; i < 4; ++i) {
        const size_t cb = (size_t)(m0 + ty * 4 + i) * 1024 + n0 + tx * 4;
        float4 o;
        o.x = alpha * acc[i][0]; o.y = alpha * acc[i][1];
        o.z = alpha * acc[i][2]; o.w = alpha * acc[i][3];
        if (has_d) {
            float4 d4 = *(const float4*)(D + cb);
            o.x = fmaf(beta, d4.x, o.x); o.y = fmaf(beta, d4.y, o.y);
            o.z = fmaf(beta, d4.z, o.z); o.w = fmaf(beta, d4.w, o.w);
        }
        *(float4*)(Cc + cb) = o;
    }
}

__launch_bounds__(256, 1)
__global__ void ns_kernel(const float* __restrict__ Wlh, const float* __restrict__ Wrh,
                          const float* __restrict__ Wq,
                          float* __restrict__ norm2,
                          float* Xa_lh, float* Xb_lh, float* Xa_rh, float* Xb_rh,
                          float* G, float* G2, float* Wu, float* Wue,
                          unsigned int* cnt, unsigned int* gen)
{
    __shared__ float As[16][68];
    __shared__ float Bs[16][68];

    const int tid = threadIdx.x;
    const int wg  = blockIdx.x;
    const int m0  = (wg >> 4) * 64;
    const int n0  = (wg & 15) * 64;

    // ---- P0: Frobenius norm^2 partials (slice: wg*4096 + tid*4 + j*1024)
    {
        float s1 = 0.f, s2 = 0.f;
        const size_t base = (size_t)wg * 4096 + tid * 4;
#pragma unroll
        for (int j = 0; j < 4; ++j) {
            float4 w = *(const float4*)(Wlh + base + j * 1024);
            s1 += w.x * w.x + w.y * w.y + w.z * w.z + w.w * w.w;
            float4 v = *(const float4*)(Wrh + base + j * 1024);
            s2 += v.x * v.x + v.y * v.y + v.z * v.z + v.w * v.w;
        }
#pragma unroll
        for (int off = 32; off > 0; off >>= 1) {
            s1 += __shfl_xor(s1, off);
            s2 += __shfl_xor(s2, off);
        }
        if ((tid & 63) == 0) {
            atomicAdd(&norm2[0], s1);
            atomicAdd(&norm2[1], s2);
        }
    }
    ns_gbar(cnt, gen);

    // ---- P1: prescale into Xa
    {
        const float sl = 1.0f / (sqrtf(norm2[0]) + 1e-8f);
        const float sr = 1.0f / (sqrtf(norm2[1]) + 1e-8f);
        const size_t base = (size_t)wg * 4096 + tid * 4;
#pragma unroll
        for (int j = 0; j < 4; ++j) {
            float4 w = *(const float4*)(Wlh + base + j * 1024);
            w.x *= sl; w.y *= sl; w.z *= sl; w.w *= sl;
            *(float4*)(Xa_lh + base + j * 1024) = w;
            float4 v = *(const float4*)(Wrh + base + j * 1024);
            v.x *= sr; v.y *= sr; v.z *= sr; v.w *= sr;
            *(float4*)(Xa_rh + base + j * 1024) = v;
        }
    }
    ns_gbar(cnt, gen);

    // ---- 12 Newton-Schulz iterations: X <- 1.5X - 0.5 (X X^T) X
    float* Xl = Xa_lh; float* Xln = Xb_lh;
    float* Xr = Xa_rh; float* Xrn = Xb_rh;
    for (int it = 0; it < 12; ++it) {
        ns_tile(Xl, Xl, nullptr, G,  m0, n0, true, false, 1.0f, 0.0f, As, Bs);
        ns_tile(Xr, Xr, nullptr, G2, m0, n0, true, false, 1.0f, 0.0f, As, Bs);
        ns_gbar(cnt, gen);
        ns_tile(G,  Xl, Xl, Xln, m0, n0, false, true, -0.5f, 1.5f, As, Bs);
        ns_tile(G2, Xr, Xr, Xrn, m0, n0, false, true, -0.5f, 1.5f, As, Bs);
        ns_gbar(cnt, gen);
        float* t;
        t = Xl; Xl = Xln; Xln = t;
        t = Xr; Xr = Xrn; Xrn = t;
    }
    // 12 swaps (even) -> Xl = Xa_lh (O_lh), Xr = Xa_rh (O_rh); Xb_* dead.

    // ---- O2 = O_lh @ O_lh (into G);  Wu = O_rh @ Wq
    ns_tile(Xl, Xl, nullptr, G,  m0, n0, false, false, 1.0f, 0.0f, As, Bs);
    ns_tile(Xr, Wq, nullptr, Wu, m0, n0, false, false, 1.0f, 0.0f, As, Bs);
    ns_gbar(cnt, gen);
    // ---- Wue = O_lh @ Wu
    ns_tile(Xl, Wu, nullptr, Wue, m0, n0, false, false, 1.0f, 0.0f, As, Bs);
}

// ---------------------------------------------------------------------------
// Scan v6 (unchanged): k=2 steps per round trip, pre-norm c publish (exact
// math) + per-wave c-only polls so compute overlaps producer straggler spread.
// ---------------------------------------------------------------------------
#define CANARY 0xAAAAAAAAu
#define HPITCH 36             // 32-float chunk + 4 pad
#define RNDS   (T_DIM/2)      // 2048 rounds, 2 steps each
#define SLOTW  1088           // 1024 c-words + 64 partial words
#define RINGW  (4*B_DIM*SLOTW)

__global__ void scan_init_kernel(unsigned int* __restrict__ zring)
{
    const int i = blockIdx.x * 256 + threadIdx.x;   // 68 blocks
    if (i < RINGW) zring[i] = CANARY;
}

__launch_bounds__(256, 1)
__global__ void scan_kernel(const float* __restrict__ O1,    // O_lh    [1024][1024]
                            const float* __restrict__ O2,    // O_lh^2  [1024][1024]
                            const float* __restrict__ ident, // [1024]
                            const float* __restrict__ U,     // [B][T][C]
                            const float* __restrict__ Ue,    // [B][T/2][C] evenU@O1^T
                            const float* __restrict__ Uo,    // [B][T/2][C] oddU@O1^T
                            float* __restrict__ QS,          // [B][T][C]
                            unsigned int* __restrict__ zring)// [4][B][SLOTW]
{
    __shared__ float sC[32 * HPITCH];   // staged c (z_0 at r=1)
    __shared__ float sUo[32 * HPITCH];  // staged (O u_rec) row
    __shared__ float sP[4 * 48];        // per-wave dot partials [wave][8rg*6]
    __shared__ float sS[12];            // per-wave {CC,CU,UU}

    const int tid  = threadIdx.x;
    const int wg   = blockIdx.x;         // 256 WGs
    const int b    = wg >> 6;            // batch
    const int g    = wg & 63;            // dim-group
    const int d0   = g * 16;
    const int rg   = tid & 7;
    const int kg   = tid >> 3;           // 0..31
    const int wid  = tid >> 6;
    const int lane = tid & 63;

    // ---- O1 rows (d0+2rg, d0+2rg+1) and O2 rows, k in [kg*32, +32) -> regs
    float o0[32], o1[32], w0[32], w1[32];
    {
        const float* r0p = O1 + (size_t)(d0 + 2 * rg) * C_DIM + kg * 32;
        const float* r1p = r0p + C_DIM;
        const float* r2p = O2 + (size_t)(d0 + 2 * rg) * C_DIM + kg * 32;
        const float* r3p = r2p + C_DIM;
#pragma unroll
        for (int j = 0; j < 8; ++j) {
            float4 a = *(const float4*)(r0p + j * 4);
            o0[j*4+0] = a.x; o0[j*4+1] = a.y; o0[j*4+2] = a.z; o0[j*4+3] = a.w;
            float4 c = *(const float4*)(r1p + j * 4);
            o1[j*4+0] = c.x; o1[j*4+1] = c.y; o1[j*4+2] = c.z; o1[j*4+3] = c.w;
            float4 e = *(const float4*)(r2p + j * 4);
            w0[j*4+0] = e.x; w0[j*4+1] = e.y; w0[j*4+2] = e.z; w0[j*4+3] = e.w;
            float4 f = *(const float4*)(r3p + j * 4);
            w1[j*4+0] = f.x; w1[j*4+1] = f.y; w1[j*4+2] = f.z; w1[j*4+3] = f.w;
        }
    }

    const int bbase = b * SLOTW;
    float zhold = 0.f;     // tid<16: z_{2r-1}[own d] carried to next round

    for (int r = 1; r <= RNDS + 1; ++r) {
        // ---- prefetch (independent of the ring; hides under the poll)
        float4 urec4 = make_float4(0.f, 0.f, 0.f, 0.f);  // U row 2r-3 (odd)
        float4 uo4   = make_float4(0.f, 0.f, 0.f, 0.f);  // Uo row r-2
        float u_mid_s = 0.f, cm_s = 0.f, urec_s = 0.f;
        if (r >= 2) {
            urec4 = *(const float4*)(U + ((size_t)b * T_DIM + (2*r - 3)) * C_DIM + tid * 4);
            if (r <= RNDS)
                uo4 = *(const float4*)(Uo + ((size_t)b * (T_DIM/2) + (r - 2)) * C_DIM + tid * 4);
            if (tid < 16)
                urec_s = U[((size_t)b * T_DIM + (2*r - 3)) * C_DIM + d0 + tid];
        }
        if (r <= RNDS && tid < 16) {
            u_mid_s = U[((size_t)b * T_DIM + (2*r - 2)) * C_DIM + d0 + tid];
            cm_s    = Ue[((size_t)b * (T_DIM/2) + (r - 1)) * C_DIM + d0 + tid];
        }

        // ---- poll own 4 c-words only (fast exit -> per-wave overlap)
        float4 c4;
        unsigned int* sb_prev = zring + ((r - 1) & 3) * (B_DIM * SLOTW) + bbase;
        if (r == 1) {
            c4 = *(const float4*)(ident + tid * 4);      // z_0 as c; s1p=1, u_rec=0
        } else {
            unsigned long long q0, q1;
            unsigned long long* p = (unsigned long long*)(sb_prev + tid * 4);
            for (;;) {
                q0 = __hip_atomic_load(p,     __ATOMIC_RELAXED, __HIP_MEMORY_SCOPE_AGENT);
                q1 = __hip_atomic_load(p + 1, __ATOMIC_RELAXED, __HIP_MEMORY_SCOPE_AGENT);
                const unsigned long long m = q0 & q1;
                if (m & (m >> 32) & 1ull) break;
                __builtin_amdgcn_s_sleep(1);
            }
            c4.x = __uint_as_float((unsigned int)q0);
            c4.y = __uint_as_float((unsigned int)(q0 >> 32));
            c4.z = __uint_as_float((unsigned int)q1);
            c4.w = __uint_as_float((unsigned int)(q1 >> 32));
        }

        // ---- early re-poison of slot (r+1)&3
        if (r <= RNDS && tid < 16) {
            unsigned int* pn = zring + ((r + 1) & 3) * (B_DIM * SLOTW) + bbase;
            __hip_atomic_store(pn + d0 + tid, CANARY,
                               __ATOMIC_RELAXED, __HIP_MEMORY_SCOPE_AGENT);
            if (tid == 0)
                __hip_atomic_store(pn + 1024 + g, CANARY,
                                   __ATOMIC_RELAXED, __HIP_MEMORY_SCOPE_AGENT);
        }

        // ---- stage c and (O u_rec) (same-wave consumers -> no barrier)
        *(float4*)(sC  + kg * HPITCH + rg * 4) = c4;
        *(float4*)(sUo + kg * HPITCH + rg * 4) = uo4;

        // ---- local norm partials: CC=Σc², CU=Σc·u_rec, UU=Σu_rec²
        float cc = c4.x*c4.x + c4.y*c4.y + c4.z*c4.z + c4.w*c4.w;
        float cu = c4.x*urec4.x + c4.y*urec4.y + c4.z*urec4.z + c4.w*urec4.w;
        float uu = urec4.x*urec4.x + urec4.y*urec4.y + urec4.z*urec4.z + urec4.w*urec4.w;
#pragma unroll
        for (int off = 32; off > 0; off >>= 1) {
            cc += __shfl_xor(cc, off);
            cu += __shfl_xor(cu, off);
            uu += __shfl_xor(uu, off);
        }
        if (lane == 0) { sS[wid*3+0] = cc; sS[wid*3+1] = cu; sS[wid*3+2] = uu; }

        // ---- triple matvec on raw operands: {c x O1, c x O2, Uo-row x O1}
        if (r <= RNDS) {
            const float* zb = sC  + kg * HPITCH;
            const float* ub = sUo + kg * HPITCH;
            float aa0 = 0.f, aa1 = 0.f, ab0 = 0.f, ab1 = 0.f, ac0 = 0.f, ac1 = 0.f;
#pragma unroll
            for (int j = 0; j < 8; ++j) {
                float4 h4 = *(const float4*)(zb + j * 4);
                float4 u4 = *(const float4*)(ub + j * 4);
                aa0 = fmaf(o0[j*4+0], h4.x, aa0); aa0 = fmaf(o0[j*4+1], h4.y, aa0);
                aa0 = fmaf(o0[j*4+2], h4.z, aa0); aa0 = fmaf(o0[j*4+3], h4.w, aa0);
                aa1 = fmaf(o1[j*4+0], h4.x, aa1); aa1 = fmaf(o1[j*4+1], h4.y, aa1);
                aa1 = fmaf(o1[j*4+2], h4.z, aa1); aa1 = fmaf(o1[j*4+3], h4.w, aa1);
                ab0 = fmaf(w0[j*4+0], h4.x, ab0); ab0 = fmaf(w0[j*4+1], h4.y, ab0);
                ab0 = fmaf(w0[j*4+2], h4.z, ab0); ab0 = fmaf(w0[j*4+3], h4.w, ab0);
                ab1 = fmaf(w1[j*4+0], h4.x, ab1); ab1 = fmaf(w1[j*4+1], h4.y, ab1);
                ab1 = fmaf(w1[j*4+2], h4.z, ab1); ab1 = fmaf(w1[j*4+3], h4.w, ab1);
                ac0 = fmaf(o0[j*4+0], u4.x, ac0); ac0 = fmaf(o0[j*4+1], u4.y, ac0);
                ac0 = fmaf(o0[j*4+2], u4.z, ac0); ac0 = fmaf(o0[j*4+3], u4.w, ac0);
                ac1 = fmaf(o1[j*4+0], u4.x, ac1); ac1 = fmaf(o1[j*4+1], u4.y, ac1);
                ac1 = fmaf(o1[j*4+2], u4.z, ac1); ac1 = fmaf(o1[j*4+3], u4.w, ac1);
            }
            aa0 += __shfl_xor(aa0, 8);  aa1 += __shfl_xor(aa1, 8);
            ab0 += __shfl_xor(ab0, 8);  ab1 += __shfl_xor(ab1, 8);
            ac0 += __shfl_xor(ac0, 8);  ac1 += __shfl_xor(ac1, 8);
            aa0 += __shfl_xor(aa0, 16); aa1 += __shfl_xor(aa1, 16);
            ab0 += __shfl_xor(ab0, 16); ab1 += __shfl_xor(ab1, 16);
            ac0 += __shfl_xor(ac0, 16); ac1 += __shfl_xor(ac1, 16);
            aa0 += __shfl_xor(aa0, 32); aa1 += __shfl_xor(aa1, 32);
            ab0 += __shfl_xor(ab0, 32); ab1 += __shfl_xor(ab1, 32);
            ac0 += __shfl_xor(ac0, 32); ac1 += __shfl_xor(ac1, 32);
            if (lane < 8) {
                float* sp = sP + wid * 48 + rg * 6;
                sp[0] = aa0; sp[1] = aa1; sp[2] = ab0;
                sp[3] = ab1; sp[4] = ac0; sp[5] = ac1;
            }
        }

        // ---- wave 0 only: poll the 64 norm partials AFTER the matvec
        float s1p = 1.0f;
        if (r >= 2 && wid == 0 && lane < 16) {
            unsigned long long q2, q3;
            unsigned long long* pp = (unsigned long long*)(sb_prev + 1024 + lane * 4);
            for (;;) {
                q2 = __hip_atomic_load(pp,     __ATOMIC_RELAXED, __HIP_MEMORY_SCOPE_AGENT);
                q3 = __hip_atomic_load(pp + 1, __ATOMIC_RELAXED, __HIP_MEMORY_SCOPE_AGENT);
                const unsigned long long m = q2 & q3;
                if (m & (m >> 32) & 1ull) break;
                __builtin_amdgcn_s_sleep(1);
            }
            float psum = __uint_as_float((unsigned)q2) + __uint_as_float((unsigned)(q2 >> 32))
                       + __uint_as_float((unsigned)q3) + __uint_as_float((unsigned)(q3 >> 32));
            psum += __shfl_xor(psum, 1);
            psum += __shfl_xor(psum, 2);
            psum += __shfl_xor(psum, 4);
            psum += __shfl_xor(psum, 8);
            s1p = 1.0f / sqrtf(psum * (1.0f / 1024.0f) + 1e-6f);
        }
        __syncthreads();   // sS + sP + cross-wave sC/sUo visible

        if (tid < 16) {
            const int k = d0 + tid;
            float s0 = 1.0f;
            if (r >= 2) {
                const float CC = sS[0] + sS[3] + sS[6] + sS[9];
                const float CU = sS[1] + sS[4] + sS[7] + sS[10];
                const float UU = sS[2] + sS[5] + sS[8] + sS[11];
                float nz = fmaf(s1p * s1p, CC, fmaf(2.0f * s1p, CU, UU));
                nz = fmaxf(nz, 0.0f);
                s0 = 1.0f / sqrtf(nz * (1.0f / 1024.0f) + 1e-6f);
            }
            const float zhold_prev = zhold;   // z_{2r-3}[d] from last round

            if (r <= RNDS) {
                const int rgi = tid >> 1, sel = tid & 1;
                float da = 0.f, db = 0.f, dc = 0.f;
#pragma unroll
                for (int w2 = 0; w2 < 4; ++w2) {
                    const float* sp = sP + w2 * 48 + rgi * 6;
                    da += sp[sel]; db += sp[2 + sel]; dc += sp[4 + sel];
                }
                const float a2r = sUo[(k >> 5) * HPITCH + (k & 31)];      // (O u_rec)[d]
                const float zmid = fmaf(s0, fmaf(s1p, da, a2r), u_mid_s); // z_{2r-1}[d]
                const float cpub = fmaf(s0, fmaf(s1p, db, dc), cm_s);     // (O z_{2r-1})[d]
                float pv = zmid * zmid;
                pv += __shfl_xor(pv, 1); pv += __shfl_xor(pv, 2);
                pv += __shfl_xor(pv, 4); pv += __shfl_xor(pv, 8);

                asm volatile("" ::: "memory");
                __builtin_amdgcn_s_waitcnt(0x0F70);   // vmcnt(0): poisons drained
                asm volatile("" ::: "memory");
                unsigned int* sb = zring + (r & 3) * (B_DIM * SLOTW) + bbase;
                __hip_atomic_store(sb + d0 + tid, __float_as_uint(cpub) | 1u,
                                   __ATOMIC_RELAXED, __HIP_MEMORY_SCOPE_AGENT);
                if (tid == 0)
                    __hip_atomic_store(sb + 1024 + g, __float_as_uint(pv) | 1u,
                                       __ATOMIC_RELAXED, __HIP_MEMORY_SCOPE_AGENT);
                zhold = zmid;
            }

            // ---- QS outputs AFTER publish (off the critical path)
            if (r >= 2) {
                // h_{2r-3} = s_{2r-3} * z_{2r-3}   (s1p is exactly s_{2r-3})
                QS[((size_t)b * T_DIM + (2*r - 4)) * C_DIM + k] = s1p * zhold_prev;
                // h_{2r-2} = s_{2r-2} * z_{2r-2},  z_{2r-2} = s1p*c + u_rec
                QS[((size_t)b * T_DIM + (2*r - 3)) * C_DIM + k] =
                    s0 * fmaf(s1p, sC[(k >> 5) * HPITCH + (k & 31)], urec_s);
            }
        }
        // no bottom barrier: racing waves spin on the next poll, which cannot
        // succeed until wave 0's publish above has issued.
    }
}

// ---------------------------------------------------------------------------
extern "C" void kernel_launch(void* const* d_in, const int* in_sizes, int n_in,
                              void* d_out, int out_size, void* d_ws, size_t ws_size,
                              hipStream_t stream)
{
    (void)in_sizes; (void)n_in; (void)out_size;

    const float* x     = (const float*)d_in[0];
    const float* Wq    = (const float*)d_in[1];
    const float* Wv    = (const float*)d_in[2];
    const float* Wc    = (const float*)d_in[3];
    const float* ident = (const float*)d_in[4];
    const float* Wlh   = (const float*)d_in[5];
    const float* Wrh   = (const float*)d_in[6];

    char* ws = (char*)d_ws;
    float*        norm2 = (float*)(ws + 256);
    unsigned int* bcnt  = (unsigned int*)(ws + 512);
    unsigned int* bgen  = (unsigned int*)(ws + 516);
    unsigned int* zring = (unsigned int*)(ws + 4096);   // 68 KB (RINGW words)
    float* Xa_lh = (float*)(ws + (size_t)128 * 1024);
    float* Xb_lh = Xa_lh + 1048576;
    float* Xa_rh = Xb_lh + 1048576;
    float* Xb_rh = Xa_rh + 1048576;
    float* G     = Xb_rh + 1048576;

    const size_t batched_need = (size_t)128 * 1024 + 6u * 4194304u + 67108864u;
    const bool batched = ws_size >= batched_need;

    float* G2 = G + (batched ? 1048576 : 0);           // only valid if batched
    float* V  = G + (batched ? 2 * 1048576 : 1048576); // 64 MB
    float* Ue = V;             // 32 MB, alive only during the scan
    float* Uo = V + 8388608;   // 32 MB, alive only during the scan

    float* out   = (float*)d_out;
    float* Ybuf  = out;          // first half: u, then Y
    float* QSbuf = out + BTC;    // second half: qs

    const int n2 = C_DIM * C_DIM;
    const dim3 blk(256);

    hipMemsetAsync(ws, 0, 4096, stream);   // norm2 + barrier words

    // --- ring init: poison everything (round 1 reads ident directly)
    scan_init_kernel<<<dim3(68), blk, 0, stream>>>(zring);

    // Wu -> Xb_lh, Wue -> Xb_rh (both dead after NS iterations)
    float* Wu  = Xb_lh;
    float* Wue = Xb_rh;

    if (batched) {
        // --- persistent Newton-Schulz (+O2, Wu, Wue) in ONE dispatch
        ns_kernel<<<dim3(256), blk, 0, stream>>>(
            Wlh, Wrh, Wq, norm2, Xa_lh, Xb_lh, Xa_rh, Xb_rh,
            G, G2, Wu, Wue, bcnt, bgen);
    } else {
        // --- fallback: multi-dispatch NS chain
        norm2_kernel<<<dim3(256), blk, 0, stream>>>(Wlh, &norm2[0], n2);
        norm2_kernel<<<dim3(256), blk, 0, stream>>>(Wrh, &norm2[1], n2);
        scale_kernel<<<dim3(1024), blk, 0, stream>>>(Wlh, &norm2[0], Xa_lh, n2);
        scale_kernel<<<dim3(1024), blk, 0, stream>>>(Wrh, &norm2[1], Xa_rh, n2);
        float* Xl = Xa_lh; float* Xln = Xb_lh;
        float* Xr = Xa_rh; float* Xrn = Xb_rh;
        const dim3 g64(16, 16);
        for (int it = 0; it < 12; ++it) {
            mm_kernel<64,64,16,4,4,true ,false,false><<<g64, blk, 0, stream>>>(
                Xl, Xl, nullptr, nullptr, G, 1024, 1024, 1024, 1024, 1.0f, 0.0f);
            mm_kernel<64,64,16,4,4,false,false,true ><<<g64, blk, 0, stream>>>(
                G, Xl, nullptr, Xl, Xln, 1024, 1024, 1024, 1024, -0.5f, 1.5f);
            mm_kernel<64,64,16,4,4,true ,false,false><<<g64, blk, 0, stream>>>(
                Xr, Xr, nullptr, nullptr, G, 1024, 1024, 1024, 1024, 1.0f, 0.0f);
            mm_kernel<64,64,16,4,4,false,false,true ><<<g64, blk, 0, stream>>>(
                G, Xr, nullptr, Xr, Xrn, 1024, 1024, 1024, 1024, -0.5f, 1.5f);
            float* tmp;
            tmp = Xl; Xl = Xln; Xln = tmp;
            tmp = Xr; Xr = Xrn; Xrn = tmp;
        }
        // O2, Wu, Wue
        mm_kernel<64,64,16,4,4,false,false,false><<<g64, blk, 0, stream>>>(
            Xa_lh, Xa_lh, nullptr, nullptr, G, 1024, 1024, 1024, 1024, 1.0f, 0.0f);
        mm_kernel<64,64,16,4,4,false,false,false><<<g64, blk, 0, stream>>>(
            Xa_rh, Wq, nullptr, nullptr, Wu, 1024, 1024, 1024, 1024, 1.0f, 0.0f);
        mm_kernel<64,64,16,4,4,false,false,false><<<g64, blk, 0, stream>>>(
            Xa_lh, Wu, nullptr, nullptr, Wue, 1024, 1024, 1024, 1024, 1.0f, 0.0f);
    }
    // Now: O_lh = Xa_lh, O_rh = Xa_rh, O2 = G, Wu = Xb_lh, Wue = Xb_rh.

    // --- u = x Wu^T (into Y half)
    const dim3 gbig(C_DIM / 128, BT / 128);
    mm_kernel<128,128,16,8,8,true,false,false><<<gbig, blk, 0, stream>>>(
        x, Wu, nullptr, nullptr, Ybuf, BT, C_DIM, C_DIM, C_DIM, 1.0f, 0.0f);

    // --- Ue = even(x)@Wue^T, Uo = odd(x)@Wue^T (lda=2048 strides rows)
    mm2_kernel<128,128,16,8,8,true,false,false><<<dim3(8, 64, 2), blk, 0, stream>>>(
        x, x + C_DIM, Wue, Wue, nullptr, nullptr, Ue, Uo,
        8192, C_DIM, C_DIM, 2048, 1.0f, 0.0f);

    // --- sequential scan (persistent, spin-on-data, 2 steps per round trip)
    scan_kernel<<<dim3(256), blk, 0, stream>>>(Xa_lh, G, ident, Ybuf, Ue, Uo,
                                               QSbuf, zring);

    // --- v = x Wv^T (into V, overwriting the dead Ue/Uo), then
    //     Y = (qs * v) Wc^T  (overwrites u region)
    mm_kernel<128,128,16,8,8,true,false,false><<<gbig, blk, 0, stream>>>(
        x, Wv, nullptr, nullptr, V, BT, C_DIM, C_DIM, C_DIM, 1.0f, 0.0f);
    mm_kernel<128,128,16,8,8,true,true,false><<<gbig, blk, 0, stream>>>(
        QSbuf, Wc, V, nullptr, Ybuf, BT, C_DIM, C_DIM, C_DIM, 1.0f, 0.0f);
}

// Round 6
// 9644.106 us; speedup vs baseline: 1.2496x; 1.2496x over previous
//
#include <hip/hip_runtime.h>
#include <math.h>

#define B_DIM 4
#define T_DIM 4096
#define C_DIM 1024
#define BT    (B_DIM*T_DIM)              // 16384
#define BTC   ((size_t)BT*(size_t)C_DIM) // 16777216

// ---------------------------------------------------------------------------
// Generic fp32 tiled matmul body (shared by single and batched wrappers).
//   TB=1: C[m,n] = sum_k A[m,k]*B[n,k]      (B stored [N,K] row-major)
//   TB=0: C[m,n] = sum_k A[m,k]*B[k,n]
//   HAS_A2: A_eff[m,k] = A[m,k]*A2[m,k]
//   out = alpha*acc + (HAS_D ? beta*D[m,n] : 0)
//   lda: row stride (elements) of A/A2 — 2048 GEMMs the even/odd rows of a
//        [16384][1024] matrix.
// ---------------------------------------------------------------------------
template<int BM, int BN, int BK, int TM, int TN, bool TB, bool HAS_A2, bool HAS_D>
__device__ __forceinline__ void mm_body(const float* __restrict__ A,
                                        const float* __restrict__ Bmat,
                                        const float* __restrict__ A2,
                                        const float* __restrict__ Dmat,
                                        float* __restrict__ C,
                                        int M, int N, int K, int lda,
                                        float alpha, float beta)
{
    constexpr int NG = TN / 4;
    __shared__ float As[BK][BM + 4];
    __shared__ float Bs[BK][BN + 4];

    const int tid = threadIdx.x;
    const int m0 = blockIdx.y * BM;
    const int n0 = blockIdx.x * BN;
    const int tx = tid & 15;
    const int ty = tid >> 4;

    float acc[TM][TN];
#pragma unroll
    for (int i = 0; i < TM; ++i)
#pragma unroll
        for (int j = 0; j < TN; ++j) acc[i][j] = 0.f;

    for (int k0 = 0; k0 < K; k0 += BK) {
        {
            const int r0 = tid >> 2;
            const int kq = (tid & 3) * 4;
#pragma unroll
            for (int r = 0; r < BM; r += 64) {
                const int row = r + r0;
                float4 a = *(const float4*)(A + (size_t)(m0 + row) * lda + k0 + kq);
                if (HAS_A2) {
                    float4 a2 = *(const float4*)(A2 + (size_t)(m0 + row) * lda + k0 + kq);
                    a.x *= a2.x; a.y *= a2.y; a.z *= a2.z; a.w *= a2.w;
                }
                As[kq + 0][row] = a.x; As[kq + 1][row] = a.y;
                As[kq + 2][row] = a.z; As[kq + 3][row] = a.w;
            }
        }
        if (TB) {
            const int r0 = tid >> 2;
            const int kq = (tid & 3) * 4;
#pragma unroll
            for (int r = 0; r < BN; r += 64) {
                const int row = r + r0;
                float4 b = *(const float4*)(Bmat + (size_t)(n0 + row) * K + k0 + kq);
                Bs[kq + 0][row] = b.x; Bs[kq + 1][row] = b.y;
                Bs[kq + 2][row] = b.z; Bs[kq + 3][row] = b.w;
            }
        } else {
            constexpr int CPR = BN / 4;
            constexpr int RPP = 256 / CPR;
            const int rr = tid / CPR;
            const int cc = (tid % CPR) * 4;
#pragma unroll
            for (int r = 0; r < BK; r += RPP) {
                float4 b = *(const float4*)(Bmat + (size_t)(k0 + r + rr) * N + n0 + cc);
                *(float4*)(&Bs[r + rr][cc]) = b;
            }
        }
        __syncthreads();

#pragma unroll
        for (int kk = 0; kk < BK; ++kk) {
            float a[TM], b[TN];
#pragma unroll
            for (int i = 0; i < TM; i += 4)
                *(float4*)(&a[i]) = *(const float4*)(&As[kk][ty * TM + i]);
#pragma unroll
            for (int g = 0; g < NG; ++g)
                *(float4*)(&b[g * 4]) = *(const float4*)(&Bs[kk][g * (BN / 2) + tx * 4]);
#pragma unroll
            for (int i = 0; i < TM; ++i)
#pragma unroll
                for (int j = 0; j < TN; ++j)
                    acc[i][j] = fmaf(a[i], b[j], acc[i][j]);
        }
        __syncthreads();
    }

#pragma unroll
    for (int i = 0; i < TM; ++i) {
        const size_t rbase = (size_t)(m0 + ty * TM + i) * N + n0;
#pragma unroll
        for (int g = 0; g < NG; ++g) {
            const size_t cb = rbase + g * (BN / 2) + tx * 4;
            float4 o;
            o.x = alpha * acc[i][g * 4 + 0];
            o.y = alpha * acc[i][g * 4 + 1];
            o.z = alpha * acc[i][g * 4 + 2];
            o.w = alpha * acc[i][g * 4 + 3];
            if (HAS_D) {
                float4 d4 = *(const float4*)(Dmat + cb);
                o.x = fmaf(beta, d4.x, o.x); o.y = fmaf(beta, d4.y, o.y);
                o.z = fmaf(beta, d4.z, o.z); o.w = fmaf(beta, d4.w, o.w);
            }
            *(float4*)(C + cb) = o;
        }
    }
}

template<int BM, int BN, int BK, int TM, int TN, bool TB, bool HAS_A2, bool HAS_D>
__launch_bounds__(256)
__global__ void mm_kernel(const float* __restrict__ A, const float* __restrict__ Bmat,
                          const float* __restrict__ A2, const float* __restrict__ Dmat,
                          float* __restrict__ C, int M, int N, int K, int lda,
                          float alpha, float beta)
{
    mm_body<BM,BN,BK,TM,TN,TB,HAS_A2,HAS_D>(A, Bmat, A2, Dmat, C, M, N, K, lda, alpha, beta);
}

// batched pair via blockIdx.z
template<int BM, int BN, int BK, int TM, int TN, bool TB, bool HAS_A2, bool HAS_D>
__launch_bounds__(256)
__global__ void mm2_kernel(const float* A0, const float* A1,
                           const float* B0, const float* B1,
                           const float* D0, const float* D1,
                           float* C0, float* C1,
                           int M, int N, int K, int lda, float alpha, float beta)
{
    const int z = blockIdx.z;
    mm_body<BM,BN,BK,TM,TN,TB,HAS_A2,HAS_D>(z ? A1 : A0, z ? B1 : B0, nullptr,
                                            z ? D1 : D0, z ? C1 : C0,
                                            M, N, K, lda, alpha, beta);
}

// ---------------------------------------------------------------------------
// Newton-Schulz helpers
// ---------------------------------------------------------------------------
__global__ void norm2_kernel(const float* __restrict__ W, float* __restrict__ out, int n)
{
    float ss = 0.f;
    for (int i = (blockIdx.x * 256 + threadIdx.x) * 4; i < n; i += gridDim.x * 256 * 4) {
        float4 w = *(const float4*)(W + i);
        ss += w.x * w.x + w.y * w.y + w.z * w.z + w.w * w.w;
    }
#pragma unroll
    for (int off = 32; off > 0; off >>= 1) ss += __shfl_xor(ss, off);
    __shared__ float red[4];
    if ((threadIdx.x & 63) == 0) red[threadIdx.x >> 6] = ss;
    __syncthreads();
    if (threadIdx.x == 0) atomicAdd(out, red[0] + red[1] + red[2] + red[3]);
}

__global__ void scale_kernel(const float* __restrict__ W, const float* __restrict__ norm2,
                             float* __restrict__ X, int n)
{
    const float s = 1.0f / (sqrtf(*norm2) + 1e-8f);
    const int i = (blockIdx.x * 256 + threadIdx.x) * 4;
    if (i < n) {
        float4 w = *(const float4*)(W + i);
        w.x *= s; w.y *= s; w.z *= s; w.w *= s;
        *(float4*)(X + i) = w;
    }
}

// ---------------------------------------------------------------------------
// Scan v6 (unchanged, proven): k=2 steps per global round trip, pre-norm c
// publish (exact math, no orthogonality assumption) + per-wave c-only polls
// so heavy compute overlaps producer straggler spread.
// ---------------------------------------------------------------------------
#define CANARY 0xAAAAAAAAu
#define HPITCH 36             // 32-float chunk + 4 pad
#define RNDS   (T_DIM/2)      // 2048 rounds, 2 steps each
#define SLOTW  1088           // 1024 c-words + 64 partial words
#define RINGW  (4*B_DIM*SLOTW)

__global__ void scan_init_kernel(unsigned int* __restrict__ zring)
{
    const int i = blockIdx.x * 256 + threadIdx.x;   // 68 blocks
    if (i < RINGW) zring[i] = CANARY;
}

__launch_bounds__(256, 1)
__global__ void scan_kernel(const float* __restrict__ O1,    // O_lh    [1024][1024]
                            const float* __restrict__ O2,    // O_lh^2  [1024][1024]
                            const float* __restrict__ ident, // [1024]
                            const float* __restrict__ U,     // [B][T][C]
                            const float* __restrict__ Ue,    // [B][T/2][C] evenU@O1^T
                            const float* __restrict__ Uo,    // [B][T/2][C] oddU@O1^T
                            float* __restrict__ QS,          // [B][T][C]
                            unsigned int* __restrict__ zring)// [4][B][SLOTW]
{
    __shared__ float sC[32 * HPITCH];   // staged c (z_0 at r=1)
    __shared__ float sUo[32 * HPITCH];  // staged (O u_rec) row
    __shared__ float sP[4 * 48];        // per-wave dot partials [wave][8rg*6]
    __shared__ float sS[12];            // per-wave {CC,CU,UU}

    const int tid  = threadIdx.x;
    const int wg   = blockIdx.x;         // 256 WGs
    const int b    = wg >> 6;            // batch
    const int g    = wg & 63;            // dim-group
    const int d0   = g * 16;
    const int rg   = tid & 7;
    const int kg   = tid >> 3;           // 0..31
    const int wid  = tid >> 6;
    const int lane = tid & 63;

    // ---- O1 rows (d0+2rg, d0+2rg+1) and O2 rows, k in [kg*32, +32) -> regs
    float o0[32], o1[32], w0[32], w1[32];
    {
        const float* r0p = O1 + (size_t)(d0 + 2 * rg) * C_DIM + kg * 32;
        const float* r1p = r0p + C_DIM;
        const float* r2p = O2 + (size_t)(d0 + 2 * rg) * C_DIM + kg * 32;
        const float* r3p = r2p + C_DIM;
#pragma unroll
        for (int j = 0; j < 8; ++j) {
            float4 a = *(const float4*)(r0p + j * 4);
            o0[j*4+0] = a.x; o0[j*4+1] = a.y; o0[j*4+2] = a.z; o0[j*4+3] = a.w;
            float4 c = *(const float4*)(r1p + j * 4);
            o1[j*4+0] = c.x; o1[j*4+1] = c.y; o1[j*4+2] = c.z; o1[j*4+3] = c.w;
            float4 e = *(const float4*)(r2p + j * 4);
            w0[j*4+0] = e.x; w0[j*4+1] = e.y; w0[j*4+2] = e.z; w0[j*4+3] = e.w;
            float4 f = *(const float4*)(r3p + j * 4);
            w1[j*4+0] = f.x; w1[j*4+1] = f.y; w1[j*4+2] = f.z; w1[j*4+3] = f.w;
        }
    }

    const int bbase = b * SLOTW;
    float zhold = 0.f;     // tid<16: z_{2r-1}[own d] carried to next round

    for (int r = 1; r <= RNDS + 1; ++r) {
        // ---- prefetch (independent of the ring; hides under the poll)
        float4 urec4 = make_float4(0.f, 0.f, 0.f, 0.f);  // U row 2r-3 (odd)
        float4 uo4   = make_float4(0.f, 0.f, 0.f, 0.f);  // Uo row r-2
        float u_mid_s = 0.f, cm_s = 0.f, urec_s = 0.f;
        if (r >= 2) {
            urec4 = *(const float4*)(U + ((size_t)b * T_DIM + (2*r - 3)) * C_DIM + tid * 4);
            if (r <= RNDS)
                uo4 = *(const float4*)(Uo + ((size_t)b * (T_DIM/2) + (r - 2)) * C_DIM + tid * 4);
            if (tid < 16)
                urec_s = U[((size_t)b * T_DIM + (2*r - 3)) * C_DIM + d0 + tid];
        }
        if (r <= RNDS && tid < 16) {
            u_mid_s = U[((size_t)b * T_DIM + (2*r - 2)) * C_DIM + d0 + tid];
            cm_s    = Ue[((size_t)b * (T_DIM/2) + (r - 1)) * C_DIM + d0 + tid];
        }

        // ---- poll own 4 c-words only (fast exit -> per-wave overlap)
        float4 c4;
        unsigned int* sb_prev = zring + ((r - 1) & 3) * (B_DIM * SLOTW) + bbase;
        if (r == 1) {
            c4 = *(const float4*)(ident + tid * 4);      // z_0 as c; s1p=1, u_rec=0
        } else {
            unsigned long long q0, q1;
            unsigned long long* p = (unsigned long long*)(sb_prev + tid * 4);
            for (;;) {
                q0 = __hip_atomic_load(p,     __ATOMIC_RELAXED, __HIP_MEMORY_SCOPE_AGENT);
                q1 = __hip_atomic_load(p + 1, __ATOMIC_RELAXED, __HIP_MEMORY_SCOPE_AGENT);
                const unsigned long long m = q0 & q1;
                if (m & (m >> 32) & 1ull) break;
                __builtin_amdgcn_s_sleep(1);
            }
            c4.x = __uint_as_float((unsigned int)q0);
            c4.y = __uint_as_float((unsigned int)(q0 >> 32));
            c4.z = __uint_as_float((unsigned int)q1);
            c4.w = __uint_as_float((unsigned int)(q1 >> 32));
        }

        // ---- early re-poison of slot (r+1)&3
        if (r <= RNDS && tid < 16) {
            unsigned int* pn = zring + ((r + 1) & 3) * (B_DIM * SLOTW) + bbase;
            __hip_atomic_store(pn + d0 + tid, CANARY,
                               __ATOMIC_RELAXED, __HIP_MEMORY_SCOPE_AGENT);
            if (tid == 0)
                __hip_atomic_store(pn + 1024 + g, CANARY,
                                   __ATOMIC_RELAXED, __HIP_MEMORY_SCOPE_AGENT);
        }

        // ---- stage c and (O u_rec) (same-wave consumers -> no barrier)
        *(float4*)(sC  + kg * HPITCH + rg * 4) = c4;
        *(float4*)(sUo + kg * HPITCH + rg * 4) = uo4;

        // ---- local norm partials: CC=Σc², CU=Σc·u_rec, UU=Σu_rec²
        float cc = c4.x*c4.x + c4.y*c4.y + c4.z*c4.z + c4.w*c4.w;
        float cu = c4.x*urec4.x + c4.y*urec4.y + c4.z*urec4.z + c4.w*urec4.w;
        float uu = urec4.x*urec4.x + urec4.y*urec4.y + urec4.z*urec4.z + urec4.w*urec4.w;
#pragma unroll
        for (int off = 32; off > 0; off >>= 1) {
            cc += __shfl_xor(cc, off);
            cu += __shfl_xor(cu, off);
            uu += __shfl_xor(uu, off);
        }
        if (lane == 0) { sS[wid*3+0] = cc; sS[wid*3+1] = cu; sS[wid*3+2] = uu; }

        // ---- triple matvec on raw operands: {c x O1, c x O2, Uo-row x O1}
        if (r <= RNDS) {
            const float* zb = sC  + kg * HPITCH;
            const float* ub = sUo + kg * HPITCH;
            float aa0 = 0.f, aa1 = 0.f, ab0 = 0.f, ab1 = 0.f, ac0 = 0.f, ac1 = 0.f;
#pragma unroll
            for (int j = 0; j < 8; ++j) {
                float4 h4 = *(const float4*)(zb + j * 4);
                float4 u4 = *(const float4*)(ub + j * 4);
                aa0 = fmaf(o0[j*4+0], h4.x, aa0); aa0 = fmaf(o0[j*4+1], h4.y, aa0);
                aa0 = fmaf(o0[j*4+2], h4.z, aa0); aa0 = fmaf(o0[j*4+3], h4.w, aa0);
                aa1 = fmaf(o1[j*4+0], h4.x, aa1); aa1 = fmaf(o1[j*4+1], h4.y, aa1);
                aa1 = fmaf(o1[j*4+2], h4.z, aa1); aa1 = fmaf(o1[j*4+3], h4.w, aa1);
                ab0 = fmaf(w0[j*4+0], h4.x, ab0); ab0 = fmaf(w0[j*4+1], h4.y, ab0);
                ab0 = fmaf(w0[j*4+2], h4.z, ab0); ab0 = fmaf(w0[j*4+3], h4.w, ab0);
                ab1 = fmaf(w1[j*4+0], h4.x, ab1); ab1 = fmaf(w1[j*4+1], h4.y, ab1);
                ab1 = fmaf(w1[j*4+2], h4.z, ab1); ab1 = fmaf(w1[j*4+3], h4.w, ab1);
                ac0 = fmaf(o0[j*4+0], u4.x, ac0); ac0 = fmaf(o0[j*4+1], u4.y, ac0);
                ac0 = fmaf(o0[j*4+2], u4.z, ac0); ac0 = fmaf(o0[j*4+3], u4.w, ac0);
                ac1 = fmaf(o1[j*4+0], u4.x, ac1); ac1 = fmaf(o1[j*4+1], u4.y, ac1);
                ac1 = fmaf(o1[j*4+2], u4.z, ac1); ac1 = fmaf(o1[j*4+3], u4.w, ac1);
            }
            aa0 += __shfl_xor(aa0, 8);  aa1 += __shfl_xor(aa1, 8);
            ab0 += __shfl_xor(ab0, 8);  ab1 += __shfl_xor(ab1, 8);
            ac0 += __shfl_xor(ac0, 8);  ac1 += __shfl_xor(ac1, 8);
            aa0 += __shfl_xor(aa0, 16); aa1 += __shfl_xor(aa1, 16);
            ab0 += __shfl_xor(ab0, 16); ab1 += __shfl_xor(ab1, 16);
            ac0 += __shfl_xor(ac0, 16); ac1 += __shfl_xor(ac1, 16);
            aa0 += __shfl_xor(aa0, 32); aa1 += __shfl_xor(aa1, 32);
            ab0 += __shfl_xor(ab0, 32); ab1 += __shfl_xor(ab1, 32);
            ac0 += __shfl_xor(ac0, 32); ac1 += __shfl_xor(ac1, 32);
            if (lane < 8) {
                float* sp = sP + wid * 48 + rg * 6;
                sp[0] = aa0; sp[1] = aa1; sp[2] = ab0;
                sp[3] = ab1; sp[4] = ac0; sp[5] = ac1;
            }
        }

        // ---- wave 0 only: poll the 64 norm partials AFTER the matvec
        float s1p = 1.0f;
        if (r >= 2 && wid == 0 && lane < 16) {
            unsigned long long q2, q3;
            unsigned long long* pp = (unsigned long long*)(sb_prev + 1024 + lane * 4);
            for (;;) {
                q2 = __hip_atomic_load(pp,     __ATOMIC_RELAXED, __HIP_MEMORY_SCOPE_AGENT);
                q3 = __hip_atomic_load(pp + 1, __ATOMIC_RELAXED, __HIP_MEMORY_SCOPE_AGENT);
                const unsigned long long m = q2 & q3;
                if (m & (m >> 32) & 1ull) break;
                __builtin_amdgcn_s_sleep(1);
            }
            float psum = __uint_as_float((unsigned)q2) + __uint_as_float((unsigned)(q2 >> 32))
                       + __uint_as_float((unsigned)q3) + __uint_as_float((unsigned)(q3 >> 32));
            psum += __shfl_xor(psum, 1);
            psum += __shfl_xor(psum, 2);
            psum += __shfl_xor(psum, 4);
            psum += __shfl_xor(psum, 8);
            s1p = 1.0f / sqrtf(psum * (1.0f / 1024.0f) + 1e-6f);
        }
        __syncthreads();   // sS + sP + cross-wave sC/sUo visible

        if (tid < 16) {
            const int k = d0 + tid;
            float s0 = 1.0f;
            if (r >= 2) {
                const float CC = sS[0] + sS[3] + sS[6] + sS[9];
                const float CU = sS[1] + sS[4] + sS[7] + sS[10];
                const float UU = sS[2] + sS[5] + sS[8] + sS[11];
                float nz = fmaf(s1p * s1p, CC, fmaf(2.0f * s1p, CU, UU));
                nz = fmaxf(nz, 0.0f);
                s0 = 1.0f / sqrtf(nz * (1.0f / 1024.0f) + 1e-6f);
            }
            const float zhold_prev = zhold;   // z_{2r-3}[d] from last round

            if (r <= RNDS) {
                const int rgi = tid >> 1, sel = tid & 1;
                float da = 0.f, db = 0.f, dc = 0.f;
#pragma unroll
                for (int w2 = 0; w2 < 4; ++w2) {
                    const float* sp = sP + w2 * 48 + rgi * 6;
                    da += sp[sel]; db += sp[2 + sel]; dc += sp[4 + sel];
                }
                const float a2r = sUo[(k >> 5) * HPITCH + (k & 31)];      // (O u_rec)[d]
                const float zmid = fmaf(s0, fmaf(s1p, da, a2r), u_mid_s); // z_{2r-1}[d]
                const float cpub = fmaf(s0, fmaf(s1p, db, dc), cm_s);     // (O z_{2r-1})[d]
                float pv = zmid * zmid;
                pv += __shfl_xor(pv, 1); pv += __shfl_xor(pv, 2);
                pv += __shfl_xor(pv, 4); pv += __shfl_xor(pv, 8);

                asm volatile("" ::: "memory");
                __builtin_amdgcn_s_waitcnt(0x0F70);   // vmcnt(0): poisons drained
                asm volatile("" ::: "memory");
                unsigned int* sb = zring + (r & 3) * (B_DIM * SLOTW) + bbase;
                __hip_atomic_store(sb + d0 + tid, __float_as_uint(cpub) | 1u,
                                   __ATOMIC_RELAXED, __HIP_MEMORY_SCOPE_AGENT);
                if (tid == 0)
                    __hip_atomic_store(sb + 1024 + g, __float_as_uint(pv) | 1u,
                                       __ATOMIC_RELAXED, __HIP_MEMORY_SCOPE_AGENT);
                zhold = zmid;
            }

            // ---- QS outputs AFTER publish (off the critical path)
            if (r >= 2) {
                // h_{2r-3} = s_{2r-3} * z_{2r-3}   (s1p is exactly s_{2r-3})
                QS[((size_t)b * T_DIM + (2*r - 4)) * C_DIM + k] = s1p * zhold_prev;
                // h_{2r-2} = s_{2r-2} * z_{2r-2},  z_{2r-2} = s1p*c + u_rec
                QS[((size_t)b * T_DIM + (2*r - 3)) * C_DIM + k] =
                    s0 * fmaf(s1p, sC[(k >> 5) * HPITCH + (k & 31)], urec_s);
            }
        }
        // no bottom barrier: racing waves spin on the next poll, which cannot
        // succeed until wave 0's publish above has issued.
    }
}

// ---------------------------------------------------------------------------
extern "C" void kernel_launch(void* const* d_in, const int* in_sizes, int n_in,
                              void* d_out, int out_size, void* d_ws, size_t ws_size,
                              hipStream_t stream)
{
    (void)in_sizes; (void)n_in; (void)out_size;

    const float* x     = (const float*)d_in[0];
    const float* Wq    = (const float*)d_in[1];
    const float* Wv    = (const float*)d_in[2];
    const float* Wc    = (const float*)d_in[3];
    const float* ident = (const float*)d_in[4];
    const float* Wlh   = (const float*)d_in[5];
    const float* Wrh   = (const float*)d_in[6];

    char* ws = (char*)d_ws;
    float*        norm2 = (float*)(ws + 256);
    unsigned int* zring = (unsigned int*)(ws + 4096);   // 68 KB (RINGW words)
    float* Xa_lh = (float*)(ws + (size_t)128 * 1024);
    float* Xb_lh = Xa_lh + 1048576;
    float* Xa_rh = Xb_lh + 1048576;
    float* Xb_rh = Xa_rh + 1048576;
    float* G     = Xb_rh + 1048576;

    const size_t batched_need = (size_t)128 * 1024 + 6u * 4194304u + 67108864u;
    const bool batched = ws_size >= batched_need;

    float* G2 = G + (batched ? 1048576 : 0);           // only valid if batched
    float* V  = G + (batched ? 2 * 1048576 : 1048576); // 64 MB
    float* Ue = V;             // 32 MB, alive only during the scan
    float* Uo = V + 8388608;   // 32 MB, alive only during the scan

    float* out   = (float*)d_out;
    float* Ybuf  = out;          // first half: u, then Y
    float* QSbuf = out + BTC;    // second half: qs

    const int n2 = C_DIM * C_DIM;
    const dim3 blk(256);

    hipMemsetAsync(ws, 0, 4096, stream);   // norm2 accumulators

    // --- Newton-Schulz prescale
    norm2_kernel<<<dim3(256), blk, 0, stream>>>(Wlh, &norm2[0], n2);
    norm2_kernel<<<dim3(256), blk, 0, stream>>>(Wrh, &norm2[1], n2);
    scale_kernel<<<dim3(1024), blk, 0, stream>>>(Wlh, &norm2[0], Xa_lh, n2);
    scale_kernel<<<dim3(1024), blk, 0, stream>>>(Wrh, &norm2[1], Xa_rh, n2);

    // --- ring init: poison everything (round 1 reads ident directly)
    scan_init_kernel<<<dim3(68), blk, 0, stream>>>(zring);

    // --- Newton-Schulz iterations: X <- 1.5X - 0.5 (X X^T) X
    //     (batched lh/rh pairs -> 512 WGs/dispatch, 2 WG/CU: best measured)
    float* Xl = Xa_lh; float* Xln = Xb_lh;
    float* Xr = Xa_rh; float* Xrn = Xb_rh;
    if (batched) {
        const dim3 g64b(16, 16, 2);
        for (int it = 0; it < 12; ++it) {
            mm2_kernel<64,64,16,4,4,true ,false,false><<<g64b, blk, 0, stream>>>(
                Xl, Xr, Xl, Xr, nullptr, nullptr, G, G2, 1024, 1024, 1024, 1024, 1.0f, 0.0f);
            mm2_kernel<64,64,16,4,4,false,false,true ><<<g64b, blk, 0, stream>>>(
                G, G2, Xl, Xr, Xl, Xr, Xln, Xrn, 1024, 1024, 1024, 1024, -0.5f, 1.5f);
            float* tmp;
            tmp = Xl; Xl = Xln; Xln = tmp;
            tmp = Xr; Xr = Xrn; Xrn = tmp;
        }
    } else {
        const dim3 g64(16, 16);
        for (int it = 0; it < 12; ++it) {
            mm_kernel<64,64,16,4,4,true ,false,false><<<g64, blk, 0, stream>>>(
                Xl, Xl, nullptr, nullptr, G, 1024, 1024, 1024, 1024, 1.0f, 0.0f);
            mm_kernel<64,64,16,4,4,false,false,true ><<<g64, blk, 0, stream>>>(
                G, Xl, nullptr, Xl, Xln, 1024, 1024, 1024, 1024, -0.5f, 1.5f);
            mm_kernel<64,64,16,4,4,true ,false,false><<<g64, blk, 0, stream>>>(
                Xr, Xr, nullptr, nullptr, G, 1024, 1024, 1024, 1024, 1.0f, 0.0f);
            mm_kernel<64,64,16,4,4,false,false,true ><<<g64, blk, 0, stream>>>(
                G, Xr, nullptr, Xr, Xrn, 1024, 1024, 1024, 1024, -0.5f, 1.5f);
            float* tmp;
            tmp = Xl; Xl = Xln; Xln = tmp;
            tmp = Xr; Xr = Xrn; Xrn = tmp;
        }
    }
    // 12 swaps (even) -> Xl = Xa_lh = O_lh, Xr = Xa_rh = O_rh; Xb_* free.

    // --- O_lh^2 (into G, free after NS)
    const dim3 g64s(16, 16);
    mm_kernel<64,64,16,4,4,false,false,false><<<g64s, blk, 0, stream>>>(
        Xl, Xl, nullptr, nullptr, G, 1024, 1024, 1024, 1024, 1.0f, 0.0f);

    // --- collapsed projections (v7 algebra, proven):
    //     Wu  = O_rh @ Wq   (u = x Wu^T replaces q = x Wq^T; u = q O_rh^T)
    //     Wue = O_lh @ Wu   (Ue/Uo = even/odd(x) @ Wue^T)
    float* Wu  = Xb_lh;
    float* Wue = Xb_rh;
    mm_kernel<64,64,16,4,4,false,false,false><<<g64s, blk, 0, stream>>>(
        Xr, Wq, nullptr, nullptr, Wu, 1024, 1024, 1024, 1024, 1.0f, 0.0f);
    mm_kernel<64,64,16,4,4,false,false,false><<<g64s, blk, 0, stream>>>(
        Xl, Wu, nullptr, nullptr, Wue, 1024, 1024, 1024, 1024, 1.0f, 0.0f);

    // --- u = x Wu^T (into Y half)
    const dim3 gbig(C_DIM / 128, BT / 128);
    mm_kernel<128,128,16,8,8,true,false,false><<<gbig, blk, 0, stream>>>(
        x, Wu, nullptr, nullptr, Ybuf, BT, C_DIM, C_DIM, C_DIM, 1.0f, 0.0f);

    // --- Ue = even(x)@Wue^T, Uo = odd(x)@Wue^T (lda=2048 strides rows)
    mm2_kernel<128,128,16,8,8,true,false,false><<<dim3(8, 64, 2), blk, 0, stream>>>(
        x, x + C_DIM, Wue, Wue, nullptr, nullptr, Ue, Uo,
        8192, C_DIM, C_DIM, 2048, 1.0f, 0.0f);

    // --- sequential scan (persistent, spin-on-data, 2 steps per round trip)
    scan_kernel<<<dim3(256), blk, 0, stream>>>(Xl, G, ident, Ybuf, Ue, Uo,
                                               QSbuf, zring);

    // --- v = x Wv^T (into V, overwriting the dead Ue/Uo), then
    //     Y = (qs * v) Wc^T  (overwrites u region)
    mm_kernel<128,128,16,8,8,true,false,false><<<gbig, blk, 0, stream>>>(
        x, Wv, nullptr, nullptr, V, BT, C_DIM, C_DIM, C_DIM, 1.0f, 0.0f);
    mm_kernel<128,128,16,8,8,true,true,false><<<gbig, blk, 0, stream>>>(
        QSbuf, Wc, V, nullptr, Ybuf, BT, C_DIM, C_DIM, C_DIM, 1.0f, 0.0f);
}